// Round 4
// baseline (70.335 us; speedup 1.0000x reference)
//
#include <hip/hip_runtime.h>

// B=8, T=2048, C=1024, H=64 single-head causal attention, f32 in/out.
// Round 4: qkv = 8-wave blocks, global_load_lds W from pre-swizzled image,
// 2-phase pipeline w/ counted vmcnt, 4 waves/SIMD. attn = 4-way wave split
// per q-chunk, barrier-free loop, LDS merge.

typedef __attribute__((ext_vector_type(4))) short sv4;
typedef __attribute__((ext_vector_type(8))) short sv8;
typedef __attribute__((ext_vector_type(4))) float f32x4;

#define NB   8
#define TSEQ 2048
#define CDIM 1024
#define HD   64
#define MROWS (NB * TSEQ)   // 16384

__device__ __forceinline__ short f2s(float f) {
  union { float f; unsigned u; } v; v.f = f;
  unsigned u = v.u;
  u += 0x7fffu + ((u >> 16) & 1u);
  return (short)(u >> 16);
}

__device__ __forceinline__ void glds16(const short* g, short* l) {
  __builtin_amdgcn_global_load_lds(
      (const __attribute__((address_space(1))) unsigned int*)g,
      (__attribute__((address_space(3))) unsigned int*)l, 16, 0, 0);
}

// ---------------- Kernel 0: W f32 -> bf16, pre-swizzled chunk images ----
// wb layout: chunk t (64 K-cols), r = j*64+wrow (0..191), slot s (0..7):
//   wb[t*12288 + r*64 + s*8 + e] = W[j][wrow][t*64 + ((s^(wrow&7))<<3) + e]
// so qkv's global_load_lds is a LINEAR copy and B-frag reads use slot^(row&7).
__global__ __launch_bounds__(256) void wcvt(
    const float* __restrict__ Wq, const float* __restrict__ Wk,
    const float* __restrict__ Wv, short* __restrict__ wb)
{
  int i = blockIdx.x * 256 + threadIdx.x;   // 0..24575
  int t = i / 1536;
  int rem = i - t * 1536;
  int r = rem >> 3, s = rem & 7;
  int j = r >> 6, wrow = r & 63;
  const float* W = (j == 0) ? Wq : (j == 1) ? Wk : Wv;
  const float* src = W + (size_t)wrow * CDIM + t * 64 + ((s ^ (wrow & 7)) << 3);
  float4 a = *(const float4*)src;
  float4 b = *(const float4*)(src + 4);
  sv8 v = {f2s(a.x), f2s(a.y), f2s(a.z), f2s(a.w),
           f2s(b.x), f2s(b.y), f2s(b.z), f2s(b.w)};
  *(sv8*)(wb + (size_t)i * 8) = v;
}

// ---------------- Kernel 1: QKV projection ----------------
// 512 blocks x 512 threads (8 waves). Block = 32 rows, all 192 out cols.
// wave: rowg = wid>>2 (16 rows), ph = wid&3 -> 3 (j,n) pairs.
// K-chunks of 64, LDS double-buffered; W via global_load_lds; x via regs.
__global__ __launch_bounds__(512) void qkv_proj(
    const float* __restrict__ x,
    const short* __restrict__ wb,
    short* __restrict__ qw,         // [MROWS][64] bf16 (q * 1/32 folded)
    short* __restrict__ kw,         // [MROWS][64] bf16
    short* __restrict__ vtw)        // [NB][64][TSEQ] bf16
{
  __shared__ short wlds[2][12288];  // 48 KB
  __shared__ short xlds[2][2048];   // 8 KB
  const int tid  = threadIdx.x;
  const int wid  = tid >> 6;
  const int lane = tid & 63;
  const int g    = lane >> 4;
  const int c16  = lane & 15;
  const int rowg = wid >> 2;
  const int ph   = wid & 3;
  const int row0 = blockIdx.x * 32;

  // x loader: thread covers row xr, 4 floats at col xs*4 (per chunk)
  const int xr = tid >> 4, xs = tid & 15;
  const float* xsrc = x + (size_t)(row0 + xr) * CDIM + xs * 4;
  const int xwo = xr * 64 + ((((xs >> 1) ^ (xr & 7))) << 3) + (xs & 1) * 4;

  const int arow = rowg * 16 + c16;
  const int x7   = c16 & 7;
  int rWo[3];
  #pragma unroll
  for (int p6 = 0; p6 < 3; ++p6) {
    int p = ph * 3 + p6;
    rWo[p6] = (((p >> 2) << 6) + ((p & 3) << 4) + c16) * 64;
  }

  f32x4 acc[3];
  #pragma unroll
  for (int p6 = 0; p6 < 3; ++p6) acc[p6] = (f32x4){0.f, 0.f, 0.f, 0.f};

  float4 px[3];

  // ---- prologue: stage chunk 0, prefetch x chunks 1,2 ----
  #pragma unroll
  for (int k2 = 0; k2 < 3; ++k2)
    glds16(wb + (size_t)(tid + k2 * 512) * 8, &wlds[0][(tid + k2 * 512) * 8]);
  px[0] = *(const float4*)(xsrc);
  px[1] = *(const float4*)(xsrc + 64);
  px[2] = *(const float4*)(xsrc + 128);
  asm volatile("s_waitcnt vmcnt(2)" ::: "memory");   // W0 glds + px[0] done
  {
    sv4 v = {f2s(px[0].x), f2s(px[0].y), f2s(px[0].z), f2s(px[0].w)};
    *(sv4*)&xlds[0][xwo] = v;
  }
  asm volatile("s_waitcnt lgkmcnt(0)" ::: "memory");
  __builtin_amdgcn_sched_barrier(0);
  __builtin_amdgcn_s_barrier();

  #pragma unroll
  for (int t = 0; t < 16; ++t) {
    const int buf = t & 1;
    if (t < 15) {   // stage chunk t+1 into buf^1
      #pragma unroll
      for (int k2 = 0; k2 < 3; ++k2)
        glds16(wb + (size_t)((t + 1) * 12288 + (tid + k2 * 512) * 8),
               &wlds[buf ^ 1][(tid + k2 * 512) * 8]);
    }
    if (t < 13) px[t % 3] = *(const float4*)(xsrc + (t + 3) * 64);
    if (t < 15) {
      float4 f = px[(t + 1) % 3];
      sv4 v = {f2s(f.x), f2s(f.y), f2s(f.z), f2s(f.w)};
      *(sv4*)&xlds[buf ^ 1][xwo] = v;
    }
    // ---- compute chunk t ----
    #pragma unroll
    for (int kk = 0; kk < 2; ++kk) {
      int so = ((kk * 4 + g) ^ x7) << 3;
      sv8 a = *(const sv8*)&xlds[buf][arow * 64 + so];
      #pragma unroll
      for (int p6 = 0; p6 < 3; ++p6) {
        sv8 bfr = *(const sv8*)&wlds[buf][rWo[p6] + so];
        acc[p6] = __builtin_amdgcn_mfma_f32_16x16x32_bf16(a, bfr, acc[p6], 0, 0, 0);
      }
    }
    if (t < 15) {
      // W glds + x ds_write must be visible; keep newest x-load in flight
      if (t < 13) asm volatile("s_waitcnt vmcnt(1) lgkmcnt(0)" ::: "memory");
      else        asm volatile("s_waitcnt vmcnt(0) lgkmcnt(0)" ::: "memory");
      __builtin_amdgcn_sched_barrier(0);
      __builtin_amdgcn_s_barrier();
    }
  }

  // ---- epilogue: D row = 4g+r, col = 16n+c16 ----
  #pragma unroll
  for (int p6 = 0; p6 < 3; ++p6) {
    int p = ph * 3 + p6, j = p >> 2, n = p & 3;
    #pragma unroll
    for (int r = 0; r < 4; ++r) {
      int rr = row0 + rowg * 16 + (g << 2) + r;
      int cc = (n << 4) + c16;
      if (j == 0)      qw[(size_t)rr * HD + cc] = f2s(acc[p6][r] * 0.03125f);
      else if (j == 1) kw[(size_t)rr * HD + cc] = f2s(acc[p6][r]);
      else             vtw[((size_t)(rr >> 11) * HD + cc) * TSEQ + (rr & (TSEQ - 1))] =
                           f2s(acc[p6][r]);
    }
  }
}

// ---------------- Kernel 2: flash attention ----------------
// 1024 blocks x 4 waves. Block = one 16-row q-chunk (big chunks first).
// Wave wid takes tiles t = wid, wid+4, ... (128 keys each), direct global K/V.
// 4-way (m,l,O) merge via LDS at the end.
__global__ __launch_bounds__(256) void attn(
    const short* __restrict__ qw,
    const short* __restrict__ kw,
    const short* __restrict__ vtw,
    float* __restrict__ out)
{
  __shared__ float ofs[4][16][64];      // per-wave: P bridge (bf16) / O (f32)
  __shared__ float msh[4][16], lsh[4][16];

  const int tid  = threadIdx.x;
  const int wid  = tid >> 6;
  const int lane = tid & 63;
  const int g    = lane >> 4;
  const int c16  = lane & 15;

  const int batch = blockIdx.x & 7;
  const int c     = 127 - (blockIdx.x >> 3);
  const int q0    = c << 4;
  const size_t base = (size_t)batch * TSEQ * HD;
  const int n_c  = (c + 8) >> 3;
  const int qrow = q0 + (g << 2);

  short* myps = (short*)(&ofs[wid][0][0]);   // 4 KB per wave

  sv8 qa0 = *(const sv8*)(qw + base + (size_t)(q0 + c16) * HD + (g << 3));
  sv8 qa1 = *(const sv8*)(qw + base + (size_t)(q0 + c16) * HD + 32 + (g << 3));

  float m[4], l[4];
  f32x4 o[4];
  #pragma unroll
  for (int r = 0; r < 4; ++r) { m[r] = -1e30f; l[r] = 0.f; }
  #pragma unroll
  for (int n = 0; n < 4; ++n) o[n] = (f32x4){0.f, 0.f, 0.f, 0.f};

  for (int t = wid; t < n_c; t += 4) {
    const short* kb = kw + base + ((size_t)t * 128 + c16) * HD + (g << 3);
    f32x4 s[8];
    #pragma unroll
    for (int n = 0; n < 8; ++n) s[n] = (f32x4){0.f, 0.f, 0.f, 0.f};

    sv8 fa[8], fb[8];
    // K pass 0 (keys n*16, n=0..3)
    #pragma unroll
    for (int n = 0; n < 4; ++n) {
      fa[2 * n]     = *(const sv8*)(kb + n * 16 * HD);
      fa[2 * n + 1] = *(const sv8*)(kb + n * 16 * HD + 32);
    }
    #pragma unroll
    for (int n = 0; n < 4; ++n) {
      s[n] = __builtin_amdgcn_mfma_f32_16x16x32_bf16(qa0, fa[2 * n], s[n], 0, 0, 0);
      s[n] = __builtin_amdgcn_mfma_f32_16x16x32_bf16(qa1, fa[2 * n + 1], s[n], 0, 0, 0);
    }
    // K pass 1 (n=4..7)
    #pragma unroll
    for (int n = 0; n < 4; ++n) {
      fb[2 * n]     = *(const sv8*)(kb + (n + 4) * 16 * HD);
      fb[2 * n + 1] = *(const sv8*)(kb + (n + 4) * 16 * HD + 32);
    }
    #pragma unroll
    for (int n = 0; n < 4; ++n) {
      s[4 + n] = __builtin_amdgcn_mfma_f32_16x16x32_bf16(qa0, fb[2 * n], s[4 + n], 0, 0, 0);
      s[4 + n] = __builtin_amdgcn_mfma_f32_16x16x32_bf16(qa1, fb[2 * n + 1], s[4 + n], 0, 0, 0);
    }
    // V loads (reuse fa/fb; latency hidden under mask+softmax)
    const short* vb = vtw + ((size_t)batch * HD + c16) * TSEQ + t * 128 + (g << 3);
    #pragma unroll
    for (int kk = 0; kk < 2; ++kk)
      #pragma unroll
      for (int n = 0; n < 4; ++n)
        fa[kk * 4 + n] = *(const sv8*)(vb + (size_t)n * 16 * TSEQ + kk * 32);
    #pragma unroll
    for (int kk = 0; kk < 2; ++kk)
      #pragma unroll
      for (int n = 0; n < 4; ++n)
        fb[kk * 4 + n] = *(const sv8*)(vb + (size_t)n * 16 * TSEQ + (kk + 2) * 32);

    // mask (scale folded into q)
    #pragma unroll
    for (int n = 0; n < 8; ++n) {
      int kcol = t * 128 + (n << 4) + c16;
      #pragma unroll
      for (int r = 0; r < 4; ++r)
        s[n][r] = (kcol <= qrow + r) ? s[n][r] : -1e30f;
    }
    // online softmax
    #pragma unroll
    for (int r = 0; r < 4; ++r) {
      float mx = fmaxf(fmaxf(fmaxf(s[0][r], s[1][r]), fmaxf(s[2][r], s[3][r])),
                       fmaxf(fmaxf(s[4][r], s[5][r]), fmaxf(s[6][r], s[7][r])));
      #pragma unroll
      for (int msk = 1; msk < 16; msk <<= 1)
        mx = fmaxf(mx, __shfl_xor(mx, msk));
      float mnew  = fmaxf(m[r], mx);
      float alpha = __expf(m[r] - mnew);
      float sum = 0.f;
      #pragma unroll
      for (int n = 0; n < 8; ++n) {
        float p = __expf(s[n][r] - mnew);
        s[n][r] = p;
        sum += p;
      }
      #pragma unroll
      for (int msk = 1; msk < 16; msk <<= 1)
        sum += __shfl_xor(sum, msk);
      l[r] = l[r] * alpha + sum;
      m[r] = mnew;
      #pragma unroll
      for (int n = 0; n < 4; ++n) o[n][r] *= alpha;
      int prow = (g << 2) + r;
      #pragma unroll
      for (int n = 0; n < 8; ++n) {
        int col = (n << 4) + c16;
        myps[prow * 128 + ((((col >> 3) ^ prow) & 15) << 3) + (col & 7)] =
            f2s(s[n][r]);
      }
    }
    asm volatile("s_waitcnt lgkmcnt(0)" ::: "memory");
    __builtin_amdgcn_sched_barrier(0);
    // O += P V
    #pragma unroll
    for (int kk = 0; kk < 4; ++kk) {
      sv8 pa = *(const sv8*)&myps[c16 * 128 + ((((kk * 4 + g) ^ c16) & 15) << 3)];
      #pragma unroll
      for (int n = 0; n < 4; ++n) {
        sv8 vf = (kk < 2) ? fa[kk * 4 + n] : fb[(kk - 2) * 4 + n];
        o[n] = __builtin_amdgcn_mfma_f32_16x16x32_bf16(pa, vf, o[n], 0, 0, 0);
      }
    }
  }

  // ---- publish partials (alias P bridge as f32 O) ----
  float* myof = (float*)myps;
  #pragma unroll
  for (int r = 0; r < 4; ++r) {
    int row = (g << 2) + r;
    #pragma unroll
    for (int n = 0; n < 4; ++n)
      myof[row * 64 + (n << 4) + c16] = o[n][r];
    if (c16 == 0) { msh[wid][row] = m[r]; lsh[wid][row] = l[r]; }
  }
  __syncthreads();

  // ---- 4-way recombine; thread -> (row, 4 cols) ----
  {
    int row = tid >> 4, col0 = (tid & 15) << 2;
    const float* O0 = (const float*)ofs;
    float M = fmaxf(fmaxf(msh[0][row], msh[1][row]),
                    fmaxf(msh[2][row], msh[3][row]));
    float w0 = __expf(msh[0][row] - M), w1 = __expf(msh[1][row] - M);
    float w2 = __expf(msh[2][row] - M), w3 = __expf(msh[3][row] - M);
    float L = w0 * lsh[0][row] + w1 * lsh[1][row] + w2 * lsh[2][row] + w3 * lsh[3][row];
    float invL = 1.f / L;
    float4 res;
    float* rp = (float*)&res;
    #pragma unroll
    for (int e = 0; e < 4; ++e) {
      int idx = row * 64 + col0 + e;
      rp[e] = (O0[idx] * w0 + O0[1024 + idx] * w1 +
               O0[2048 + idx] * w2 + O0[3072 + idx] * w3) * invL;
    }
    *(float4*)(out + base + (size_t)(q0 + row) * HD + col0) = res;
  }
}

extern "C" void kernel_launch(void* const* d_in, const int* in_sizes, int n_in,
                              void* d_out, int out_size, void* d_ws, size_t ws_size,
                              hipStream_t stream) {
  const float* x  = (const float*)d_in[0];
  const float* Wk = (const float*)d_in[1];
  const float* Wq = (const float*)d_in[2];
  const float* Wv = (const float*)d_in[3];
  float* out = (float*)d_out;

  short* qw  = (short*)d_ws;                        // 2 MB
  short* kw  = qw + (size_t)MROWS * HD;             // 2 MB
  short* vtw = kw + (size_t)MROWS * HD;             // 2 MB
  short* wb  = vtw + (size_t)NB * HD * TSEQ;        // 384 KB (pre-swizzled)

  wcvt<<<dim3(96), dim3(256), 0, stream>>>(Wq, Wk, Wv, wb);
  qkv_proj<<<dim3(MROWS / 32), dim3(512), 0, stream>>>(x, wb, qw, kw, vtw);
  attn<<<dim3(1024), dim3(256), 0, stream>>>(qw, kw, vtw, out);
}

// Round 5
// 65.251 us; speedup vs baseline: 1.0779x; 1.0779x over previous
//
#include <hip/hip_runtime.h>

// B=8, T=2048, C=1024, H=64 single-head causal attention, f32 in/out.
// Round 5: attn rewritten with SWAPPED QK^T (S^T = mfma(K,Q)) so softmax is
// per-lane: 31 in-lane ops + 2+2 shfl hops (was 8 hops x 4 rows), P-bridge
// 8 ds_write_b64 (was 32 ds_write_u16). Outer structure = round-3 (512 blocks,
// chunk-pair + half split). qkv/wcvt unchanged from round 4.

typedef __attribute__((ext_vector_type(4))) short sv4;
typedef __attribute__((ext_vector_type(8))) short sv8;
typedef __attribute__((ext_vector_type(4))) float f32x4;

#define NB   8
#define TSEQ 2048
#define CDIM 1024
#define HD   64
#define MROWS (NB * TSEQ)   // 16384

__device__ __forceinline__ short f2s(float f) {
  union { float f; unsigned u; } v; v.f = f;
  unsigned u = v.u;
  u += 0x7fffu + ((u >> 16) & 1u);
  return (short)(u >> 16);
}
__device__ __forceinline__ unsigned pk2(float lo, float hi) {
  return (unsigned)(unsigned short)f2s(lo) | ((unsigned)(unsigned short)f2s(hi) << 16);
}

__device__ __forceinline__ void glds16(const short* g, short* l) {
  __builtin_amdgcn_global_load_lds(
      (const __attribute__((address_space(1))) unsigned int*)g,
      (__attribute__((address_space(3))) unsigned int*)l, 16, 0, 0);
}

// ---------------- Kernel 0: W f32 -> bf16, pre-swizzled chunk images ----
__global__ __launch_bounds__(256) void wcvt(
    const float* __restrict__ Wq, const float* __restrict__ Wk,
    const float* __restrict__ Wv, short* __restrict__ wb)
{
  int i = blockIdx.x * 256 + threadIdx.x;   // 0..24575
  int t = i / 1536;
  int rem = i - t * 1536;
  int r = rem >> 3, s = rem & 7;
  int j = r >> 6, wrow = r & 63;
  const float* W = (j == 0) ? Wq : (j == 1) ? Wk : Wv;
  const float* src = W + (size_t)wrow * CDIM + t * 64 + ((s ^ (wrow & 7)) << 3);
  float4 a = *(const float4*)src;
  float4 b = *(const float4*)(src + 4);
  sv8 v = {f2s(a.x), f2s(a.y), f2s(a.z), f2s(a.w),
           f2s(b.x), f2s(b.y), f2s(b.z), f2s(b.w)};
  *(sv8*)(wb + (size_t)i * 8) = v;
}

// ---------------- Kernel 1: QKV projection (unchanged from round 4) ----
__global__ __launch_bounds__(512) void qkv_proj(
    const float* __restrict__ x,
    const short* __restrict__ wb,
    short* __restrict__ qw,         // [MROWS][64] bf16 (q * 1/32 folded)
    short* __restrict__ kw,         // [MROWS][64] bf16
    short* __restrict__ vtw)        // [NB][64][TSEQ] bf16
{
  __shared__ short wlds[2][12288];  // 48 KB
  __shared__ short xlds[2][2048];   // 8 KB
  const int tid  = threadIdx.x;
  const int wid  = tid >> 6;
  const int lane = tid & 63;
  const int g    = lane >> 4;
  const int c16  = lane & 15;
  const int rowg = wid >> 2;
  const int ph   = wid & 3;
  const int row0 = blockIdx.x * 32;

  const int xr = tid >> 4, xs = tid & 15;
  const float* xsrc = x + (size_t)(row0 + xr) * CDIM + xs * 4;
  const int xwo = xr * 64 + ((((xs >> 1) ^ (xr & 7))) << 3) + (xs & 1) * 4;

  const int arow = rowg * 16 + c16;
  const int x7   = c16 & 7;
  int rWo[3];
  #pragma unroll
  for (int p6 = 0; p6 < 3; ++p6) {
    int p = ph * 3 + p6;
    rWo[p6] = (((p >> 2) << 6) + ((p & 3) << 4) + c16) * 64;
  }

  f32x4 acc[3];
  #pragma unroll
  for (int p6 = 0; p6 < 3; ++p6) acc[p6] = (f32x4){0.f, 0.f, 0.f, 0.f};

  float4 px[3];

  #pragma unroll
  for (int k2 = 0; k2 < 3; ++k2)
    glds16(wb + (size_t)(tid + k2 * 512) * 8, &wlds[0][(tid + k2 * 512) * 8]);
  px[0] = *(const float4*)(xsrc);
  px[1] = *(const float4*)(xsrc + 64);
  px[2] = *(const float4*)(xsrc + 128);
  asm volatile("s_waitcnt vmcnt(2)" ::: "memory");
  {
    sv4 v = {f2s(px[0].x), f2s(px[0].y), f2s(px[0].z), f2s(px[0].w)};
    *(sv4*)&xlds[0][xwo] = v;
  }
  asm volatile("s_waitcnt lgkmcnt(0)" ::: "memory");
  __builtin_amdgcn_sched_barrier(0);
  __builtin_amdgcn_s_barrier();

  #pragma unroll
  for (int t = 0; t < 16; ++t) {
    const int buf = t & 1;
    if (t < 15) {
      #pragma unroll
      for (int k2 = 0; k2 < 3; ++k2)
        glds16(wb + (size_t)((t + 1) * 12288 + (tid + k2 * 512) * 8),
               &wlds[buf ^ 1][(tid + k2 * 512) * 8]);
    }
    if (t < 13) px[t % 3] = *(const float4*)(xsrc + (t + 3) * 64);
    if (t < 15) {
      float4 f = px[(t + 1) % 3];
      sv4 v = {f2s(f.x), f2s(f.y), f2s(f.z), f2s(f.w)};
      *(sv4*)&xlds[buf ^ 1][xwo] = v;
    }
    #pragma unroll
    for (int kk = 0; kk < 2; ++kk) {
      int so = ((kk * 4 + g) ^ x7) << 3;
      sv8 a = *(const sv8*)&xlds[buf][arow * 64 + so];
      #pragma unroll
      for (int p6 = 0; p6 < 3; ++p6) {
        sv8 bfr = *(const sv8*)&wlds[buf][rWo[p6] + so];
        acc[p6] = __builtin_amdgcn_mfma_f32_16x16x32_bf16(a, bfr, acc[p6], 0, 0, 0);
      }
    }
    if (t < 15) {
      if (t < 13) asm volatile("s_waitcnt vmcnt(1) lgkmcnt(0)" ::: "memory");
      else        asm volatile("s_waitcnt vmcnt(0) lgkmcnt(0)" ::: "memory");
      __builtin_amdgcn_sched_barrier(0);
      __builtin_amdgcn_s_barrier();
    }
  }

  #pragma unroll
  for (int p6 = 0; p6 < 3; ++p6) {
    int p = ph * 3 + p6, j = p >> 2, n = p & 3;
    #pragma unroll
    for (int r = 0; r < 4; ++r) {
      int rr = row0 + rowg * 16 + (g << 2) + r;
      int cc = (n << 4) + c16;
      if (j == 0)      qw[(size_t)rr * HD + cc] = f2s(acc[p6][r] * 0.03125f);
      else if (j == 1) kw[(size_t)rr * HD + cc] = f2s(acc[p6][r]);
      else             vtw[((size_t)(rr >> 11) * HD + cc) * TSEQ + (rr & (TSEQ - 1))] =
                           f2s(acc[p6][r]);
    }
  }
}

// ---------------- Kernel 2: flash attention, swapped-QK per-lane softmax ----
// 512 blocks x 4 waves. Wave: chunk ch=wid>>1 (c = i or 127-i, 16 q rows),
// half h=wid&1 of its key range (128-key tiles). Direct-global K/V.
__global__ __launch_bounds__(256) void attn(
    const short* __restrict__ qw,
    const short* __restrict__ kw,
    const short* __restrict__ vtw,
    float* __restrict__ out)
{
  __shared__ short ps[4][2048];       // per-wave P bridge, 4 KB each
  __shared__ float cmbO[2][16][64];   // h=1 partial O
  __shared__ float cmbM[2][16], cmbL[2][16];

  const int tid  = threadIdx.x;
  const int wid  = tid >> 6;
  const int lane = tid & 63;
  const int g    = lane >> 4;
  const int c16  = lane & 15;

  const int batch = blockIdx.x & 7;
  const int i     = blockIdx.x >> 3;
  const int ch    = wid >> 1;
  const int h     = wid & 1;
  const int c     = ch ? (127 - i) : i;
  const int q0    = c << 4;
  const size_t base = (size_t)batch * TSEQ * HD;

  const int n_c = (c + 8) >> 3;
  const int th  = (n_c + 1) >> 1;
  const int t0  = h ? th : 0;
  const int t1  = h ? n_c : th;

  // Q as B-frag: lane provides col=c16 (q-row), k = 8g+j. Scale pre-folded.
  sv8 qa0 = *(const sv8*)(qw + base + (size_t)(q0 + c16) * HD + (g << 3));
  sv8 qa1 = *(const sv8*)(qw + base + (size_t)(q0 + c16) * HD + 32 + (g << 3));

  const int qrow = q0 + c16;          // this lane's q-row
  float m = -1e30f, l = 0.f;
  f32x4 o[4];
  #pragma unroll
  for (int n = 0; n < 4; ++n) o[n] = (f32x4){0.f, 0.f, 0.f, 0.f};

  char* myps = (char*)&ps[wid][0];
  const int sx = c16 & 15;            // bridge swizzle key

  for (int t = t0; t < t1; ++t) {
    const short* kb = kw + base + ((size_t)t * 128 + c16) * HD + (g << 3);
    f32x4 s[8];
    #pragma unroll
    for (int n = 0; n < 8; ++n) s[n] = (f32x4){0.f, 0.f, 0.f, 0.f};

    sv8 fa[8], fb[8];
    // K pass 0: A-frag rows = keys 16n+c16, n=0..3. SWAPPED: mfma(K, Q).
    #pragma unroll
    for (int n = 0; n < 4; ++n) {
      fa[2 * n]     = *(const sv8*)(kb + n * 16 * HD);
      fa[2 * n + 1] = *(const sv8*)(kb + n * 16 * HD + 32);
    }
    #pragma unroll
    for (int n = 0; n < 4; ++n) {
      s[n] = __builtin_amdgcn_mfma_f32_16x16x32_bf16(fa[2 * n],     qa0, s[n], 0, 0, 0);
      s[n] = __builtin_amdgcn_mfma_f32_16x16x32_bf16(fa[2 * n + 1], qa1, s[n], 0, 0, 0);
    }
    // K pass 1: n=4..7
    #pragma unroll
    for (int n = 0; n < 4; ++n) {
      fb[2 * n]     = *(const sv8*)(kb + (n + 4) * 16 * HD);
      fb[2 * n + 1] = *(const sv8*)(kb + (n + 4) * 16 * HD + 32);
    }
    #pragma unroll
    for (int n = 0; n < 4; ++n) {
      s[4 + n] = __builtin_amdgcn_mfma_f32_16x16x32_bf16(fb[2 * n],     qa0, s[4 + n], 0, 0, 0);
      s[4 + n] = __builtin_amdgcn_mfma_f32_16x16x32_bf16(fb[2 * n + 1], qa1, s[4 + n], 0, 0, 0);
    }
    // V loads (reuse fa/fb): B-frag col = d = 16n'+c16, k = key
    const short* vb = vtw + ((size_t)batch * HD + c16) * TSEQ + t * 128 + (g << 3);
    #pragma unroll
    for (int kk = 0; kk < 2; ++kk)
      #pragma unroll
      for (int n = 0; n < 4; ++n)
        fa[kk * 4 + n] = *(const sv8*)(vb + (size_t)n * 16 * TSEQ + kk * 32);
    #pragma unroll
    for (int kk = 0; kk < 2; ++kk)
      #pragma unroll
      for (int n = 0; n < 4; ++n)
        fb[kk * 4 + n] = *(const sv8*)(vb + (size_t)n * 16 * TSEQ + (kk + 2) * 32);

    // ---- mask: lane owns q-row c16, keys t*128 + 16n + 4g + r ----
    const int kb0 = t * 128 + (g << 2);
    #pragma unroll
    for (int n = 0; n < 8; ++n) {
      int key = kb0 + (n << 4);
      #pragma unroll
      for (int r = 0; r < 4; ++r)
        s[n][r] = (key + r <= qrow) ? s[n][r] : -1e30f;
    }

    // ---- per-lane online softmax ----
    float mx = -1e30f;
    #pragma unroll
    for (int n = 0; n < 8; ++n) {
      float a01 = fmaxf(s[n][0], s[n][1]);
      float a23 = fmaxf(s[n][2], s[n][3]);
      mx = fmaxf(mx, fmaxf(a01, a23));
    }
    mx = fmaxf(mx, __shfl_xor(mx, 16));
    mx = fmaxf(mx, __shfl_xor(mx, 32));
    float mnew  = fmaxf(m, mx);
    float alpha = __expf(m - mnew);
    m = mnew;

    float sum = 0.f;
    #pragma unroll
    for (int n = 0; n < 8; ++n) {
      float p0 = __expf(s[n][0] - mnew);
      float p1 = __expf(s[n][1] - mnew);
      float p2 = __expf(s[n][2] - mnew);
      float p3 = __expf(s[n][3] - mnew);
      sum += (p0 + p1) + (p2 + p3);
      // bridge write: keys 16n+4g+0..3 of row c16, b64, swizzled
      unsigned d01 = pk2(p0, p1), d23 = pk2(p2, p3);
      int slot = 2 * n + (g >> 1);
      int byte = c16 * 256 + ((slot ^ sx) << 4) + ((g & 1) << 3);
      uint2 w2; w2.x = d01; w2.y = d23;
      *(uint2*)(myps + byte) = w2;
    }
    sum += __shfl_xor(sum, 16);
    sum += __shfl_xor(sum, 32);
    l = l * alpha + sum;

    // ---- O rescale: D-rows 4g+r need alpha of q-row 4g+r ----
    float af[4];
    #pragma unroll
    for (int r = 0; r < 4; ++r) af[r] = __shfl(alpha, (g << 2) + r);
    #pragma unroll
    for (int n = 0; n < 4; ++n)
      #pragma unroll
      for (int r = 0; r < 4; ++r) o[n][r] *= af[r];

    asm volatile("s_waitcnt lgkmcnt(0)" ::: "memory");
    __builtin_amdgcn_sched_barrier(0);

    // ---- O += P V : A = P rows=q (read bridge row c16, keys 32kk+8g..) ----
    #pragma unroll
    for (int kk = 0; kk < 4; ++kk) {
      int byte = c16 * 256 + ((((kk << 2) + g) ^ sx) << 4);
      sv8 pa = *(const sv8*)(myps + byte);
      #pragma unroll
      for (int n = 0; n < 4; ++n) {
        sv8 vf = (kk < 2) ? fa[kk * 4 + n] : fb[(kk - 2) * 4 + n];
        o[n] = __builtin_amdgcn_mfma_f32_16x16x32_bf16(pa, vf, o[n], 0, 0, 0);
      }
    }
  }

  // ---- split-K combine: h=1 publishes, h=0 merges and writes ----
  if (h == 1) {
    #pragma unroll
    for (int r = 0; r < 4; ++r) {
      int row = (g << 2) + r;
      #pragma unroll
      for (int n = 0; n < 4; ++n)
        cmbO[ch][row][(n << 4) + c16] = o[n][r];
    }
    if (lane < 16) { cmbM[ch][c16] = m; cmbL[ch][c16] = l; }
  }
  __syncthreads();
  if (h == 0) {
    #pragma unroll
    for (int r = 0; r < 4; ++r) {
      int row = (g << 2) + r;
      float m0 = __shfl(m, (g << 2) + r);
      float l0 = __shfl(l, (g << 2) + r);
      float m1 = cmbM[ch][row], l1 = cmbL[ch][row];
      float M  = fmaxf(m0, m1);
      float a0 = __expf(m0 - M), a1 = __expf(m1 - M);
      float invL = 1.f / (l0 * a0 + l1 * a1);
      #pragma unroll
      for (int n = 0; n < 4; ++n) {
        float v = (o[n][r] * a0 + cmbO[ch][row][(n << 4) + c16] * a1) * invL;
        out[base + (size_t)(q0 + row) * HD + (n << 4) + c16] = v;
      }
    }
  }
}

extern "C" void kernel_launch(void* const* d_in, const int* in_sizes, int n_in,
                              void* d_out, int out_size, void* d_ws, size_t ws_size,
                              hipStream_t stream) {
  const float* x  = (const float*)d_in[0];
  const float* Wk = (const float*)d_in[1];
  const float* Wq = (const float*)d_in[2];
  const float* Wv = (const float*)d_in[3];
  float* out = (float*)d_out;

  short* qw  = (short*)d_ws;                        // 2 MB
  short* kw  = qw + (size_t)MROWS * HD;             // 2 MB
  short* vtw = kw + (size_t)MROWS * HD;             // 2 MB
  short* wb  = vtw + (size_t)NB * HD * TSEQ;        // 384 KB (pre-swizzled)

  wcvt<<<dim3(96), dim3(256), 0, stream>>>(Wq, Wk, Wv, wb);
  qkv_proj<<<dim3(MROWS / 32), dim3(512), 0, stream>>>(x, wb, qw, kw, vtw);
  attn<<<dim3(512), dim3(256), 0, stream>>>(qw, kw, vtw, out);
}

// Round 6
// 57.689 us; speedup vs baseline: 1.2192x; 1.1311x over previous
//
#include <hip/hip_runtime.h>

// B=8, T=2048, C=1024, H=64 single-head causal attention, f32 in/out.
// Round 6: attn shares K/V across 4 waves via LDS (4x less L2 traffic),
// staged with global_load_lds from PRE-SWIZZLED kw/vtw images written by qkv.
// Split-K halves (512 balanced blocks) + combine kernel. Per-lane swapped-QK
// softmax kept from R5. qkv: M=64, 1024-thr blocks (halves W re-stream).

typedef __attribute__((ext_vector_type(4))) short sv4;
typedef __attribute__((ext_vector_type(8))) short sv8;
typedef __attribute__((ext_vector_type(4))) float f32x4;

#define NB   8
#define TSEQ 2048
#define CDIM 1024
#define HD   64
#define MROWS (NB * TSEQ)   // 16384

__device__ __forceinline__ short f2s(float f) {
  union { float f; unsigned u; } v; v.f = f;
  unsigned u = v.u;
  u += 0x7fffu + ((u >> 16) & 1u);
  return (short)(u >> 16);
}
__device__ __forceinline__ unsigned pk2(float lo, float hi) {
  return (unsigned)(unsigned short)f2s(lo) | ((unsigned)(unsigned short)f2s(hi) << 16);
}
__device__ __forceinline__ void glds16(const short* g, short* l) {
  __builtin_amdgcn_global_load_lds(
      (const __attribute__((address_space(1))) unsigned int*)g,
      (__attribute__((address_space(3))) unsigned int*)l, 16, 0, 0);
}

// ---------------- Kernel 0: W f32 -> bf16, pre-swizzled chunk images ----
// wb: chunk t (64 K), r = j*64+wrow, slot s: holds W[j][wrow][t*64+((s^(wrow&7))<<3)+e]
__global__ __launch_bounds__(256) void wcvt(
    const float* __restrict__ Wq, const float* __restrict__ Wk,
    const float* __restrict__ Wv, short* __restrict__ wb)
{
  int i = blockIdx.x * 256 + threadIdx.x;   // 0..24575
  int t = i / 1536;
  int rem = i - t * 1536;
  int r = rem >> 3, s = rem & 7;
  int j = r >> 6, wrow = r & 63;
  const float* W = (j == 0) ? Wq : (j == 1) ? Wk : Wv;
  const float* src = W + (size_t)wrow * CDIM + t * 64 + ((s ^ (wrow & 7)) << 3);
  float4 a = *(const float4*)src;
  float4 b = *(const float4*)(src + 4);
  sv8 v = {f2s(a.x), f2s(a.y), f2s(a.z), f2s(a.w),
           f2s(b.x), f2s(b.y), f2s(b.z), f2s(b.w)};
  *(sv8*)(wb + (size_t)i * 8) = v;
}

// ---------------- Kernel 1: QKV projection ----------------
// 256 blocks x 1024 threads (16 waves). Block = 64 rows, 192 out cols.
// wave: rowg = wid>>2 (16 rows), ph = wid&3 -> 3 (j,n) pairs.
// Outputs: qw linear (scale folded), kw row-swizzled, vtw tile-blocked+swizzled.
__global__ __launch_bounds__(1024) void qkv_proj(
    const float* __restrict__ x,
    const short* __restrict__ wb,
    short* __restrict__ qw,
    short* __restrict__ kw,
    short* __restrict__ vtw)
{
  __shared__ short wlds[2][12288];  // 48 KB
  __shared__ short xlds[2][4096];   // 16 KB
  const int tid  = threadIdx.x;
  const int wid  = tid >> 6;
  const int lane = tid & 63;
  const int g    = lane >> 4;
  const int c16  = lane & 15;
  const int rowg = wid >> 2;
  const int ph   = wid & 3;
  const int row0 = blockIdx.x * 64;

  const int xr = tid >> 4, xs = tid & 15;
  const float* xsrc = x + (size_t)(row0 + xr) * CDIM + xs * 4;
  const int xwo = xr * 64 + (((xs >> 1) ^ (xr & 7)) << 3) + (xs & 1) * 4;

  const int arow = rowg * 16 + c16;
  const int x7   = c16 & 7;
  int rWo[3];
  #pragma unroll
  for (int p6 = 0; p6 < 3; ++p6) {
    int p = ph * 3 + p6;
    rWo[p6] = ((p >> 2) * 64 + (p & 3) * 16 + c16) * 64;
  }

  f32x4 acc[3];
  #pragma unroll
  for (int p6 = 0; p6 < 3; ++p6) acc[p6] = (f32x4){0.f, 0.f, 0.f, 0.f};

  float4 px[3];

  // prologue: stage W chunk 0 (glds), x chunks 0..2 to regs
  glds16(wb + (size_t)tid * 8, &wlds[0][tid * 8]);
  if (wid < 8) glds16(wb + (size_t)(1024 + tid) * 8, &wlds[0][(1024 + tid) * 8]);
  px[0] = *(const float4*)(xsrc);
  px[1] = *(const float4*)(xsrc + 64);
  px[2] = *(const float4*)(xsrc + 128);
  asm volatile("s_waitcnt vmcnt(2)" ::: "memory");
  {
    sv4 v = {f2s(px[0].x), f2s(px[0].y), f2s(px[0].z), f2s(px[0].w)};
    *(sv4*)&xlds[0][xwo] = v;
  }
  asm volatile("s_waitcnt lgkmcnt(0)" ::: "memory");
  __builtin_amdgcn_sched_barrier(0);
  __builtin_amdgcn_s_barrier();

  #pragma unroll
  for (int t = 0; t < 16; ++t) {
    const int buf = t & 1;
    if (t < 15) {
      glds16(wb + (size_t)(t + 1) * 12288 + tid * 8, &wlds[buf ^ 1][tid * 8]);
      if (wid < 8)
        glds16(wb + (size_t)(t + 1) * 12288 + (1024 + tid) * 8,
               &wlds[buf ^ 1][(1024 + tid) * 8]);
    }
    if (t < 13) px[t % 3] = *(const float4*)(xsrc + (t + 3) * 64);
    if (t < 15) {
      float4 f = px[(t + 1) % 3];
      sv4 v = {f2s(f.x), f2s(f.y), f2s(f.z), f2s(f.w)};
      *(sv4*)&xlds[buf ^ 1][xwo] = v;
    }
    #pragma unroll
    for (int kk = 0; kk < 2; ++kk) {
      int so = ((kk * 4 + g) ^ x7) << 3;
      sv8 a = *(const sv8*)&xlds[buf][arow * 64 + so];
      #pragma unroll
      for (int p6 = 0; p6 < 3; ++p6) {
        sv8 bfr = *(const sv8*)&wlds[buf][rWo[p6] + so];
        acc[p6] = __builtin_amdgcn_mfma_f32_16x16x32_bf16(a, bfr, acc[p6], 0, 0, 0);
      }
    }
    if (t < 15) {
      if (t < 13) asm volatile("s_waitcnt vmcnt(1) lgkmcnt(0)" ::: "memory");
      else        asm volatile("s_waitcnt vmcnt(0) lgkmcnt(0)" ::: "memory");
      __builtin_amdgcn_sched_barrier(0);
      __builtin_amdgcn_s_barrier();
    }
  }

  // epilogue: D row = 4g+r, col = 16n+c16
  #pragma unroll
  for (int p6 = 0; p6 < 3; ++p6) {
    int p = ph * 3 + p6, j = p >> 2, n = p & 3;
    #pragma unroll
    for (int r = 0; r < 4; ++r) {
      int rr = row0 + rowg * 16 + (g << 2) + r;
      int cc = (n << 4) + c16;
      if (j == 0) {
        qw[(size_t)rr * HD + cc] = f2s(acc[p6][r] * 0.03125f);
      } else if (j == 1) {
        kw[(size_t)rr * HD + ((((cc >> 3) ^ (rr & 7)) << 3) | (cc & 7))] =
            f2s(acc[p6][r]);
      } else {
        int b = rr >> 11, ti = rr & (TSEQ - 1);
        int kt = ti >> 6, key = ti & 63;
        vtw[(((size_t)b * 32 + kt) * 64 + cc) * 64 +
            ((((key >> 3) ^ (cc & 7)) << 3) | (key & 7))] = f2s(acc[p6][r]);
      }
    }
  }
}

// ---------------- Kernel 2: flash attention ----------------
// 512 blocks x 4 waves. Block = (batch, qb 64-row q-block, half h).
// K/V tiles (64 keys) shared via LDS (glds from pre-swizzled images),
// double-buffered, one barrier/tile with counted prefetch.
// h0: tiles [0,th), h1: [th, qb+1) (h1 blocks dispatched in reverse qb order
// so RR pairing balances CU load). Partials (O,m,l) -> workspace.
__global__ __launch_bounds__(256) void attn(
    const short* __restrict__ qw,
    const short* __restrict__ kw,
    const short* __restrict__ vtw,
    float* __restrict__ Opart,
    float* __restrict__ mlws)
{
  __shared__ short kbuf[2][4096];     // 16 KB
  __shared__ short vbuf[2][4096];     // 16 KB
  __shared__ short bridge[4][1024];   // 8 KB, per-wave P bridge

  const int tid  = threadIdx.x;
  const int wid  = tid >> 6;
  const int lane = tid & 63;
  const int g    = lane >> 4;
  const int c16  = lane & 15;

  const int bid   = blockIdx.x;
  const int h     = bid >> 8;
  const int sub   = bid & 255;
  const int batch = sub & 7;
  const int jj    = sub >> 3;
  const int qb    = h ? (31 - jj) : jj;
  const int q0    = qb << 6;
  const size_t base = (size_t)batch * TSEQ * HD;

  const int ntot = qb + 1;
  const int th_  = (ntot + 1) >> 1;
  const int t0   = h ? th_ : 0;
  const int t1   = h ? ntot : th_;

  const int qrow = q0 + (wid << 4) + c16;   // this lane's q-row (via D col)
  sv8 qa0 = *(const sv8*)(qw + base + (size_t)qrow * HD + (g << 3));
  sv8 qa1 = *(const sv8*)(qw + base + (size_t)qrow * HD + 32 + (g << 3));

  float m = -1e30f, l = 0.f;
  f32x4 o[4];
  #pragma unroll
  for (int n = 0; n < 4; ++n) o[n] = (f32x4){0.f, 0.f, 0.f, 0.f};

  short* br = &bridge[wid][0];
  const int sx = c16 & 7;

  #define STAGE(tt, bb)                                                      \
    {                                                                        \
      const short* ksrc = kw + base + (size_t)(tt) * 4096;                   \
      const short* vsrc = vtw + ((size_t)batch * 32 + (tt)) * 4096;          \
      glds16(ksrc + tid * 8,         &kbuf[bb][tid * 8]);                    \
      glds16(ksrc + (256 + tid) * 8, &kbuf[bb][(256 + tid) * 8]);            \
      glds16(vsrc + tid * 8,         &vbuf[bb][tid * 8]);                    \
      glds16(vsrc + (256 + tid) * 8, &vbuf[bb][(256 + tid) * 8]);            \
    }

  if (t0 < t1) {
    STAGE(t0, 0);
    asm volatile("s_waitcnt vmcnt(0)" ::: "memory");
    __builtin_amdgcn_s_barrier();

    for (int t = t0; t < t1; ++t) {
      const int buf = (t - t0) & 1;
      if (t + 1 < t1) STAGE(t + 1, buf ^ 1);

      // ---- S^T = mfma(K, Q): D[row=key, col=q] ----
      f32x4 s[4];
      #pragma unroll
      for (int n = 0; n < 4; ++n) s[n] = (f32x4){0.f, 0.f, 0.f, 0.f};
      #pragma unroll
      for (int n = 0; n < 4; ++n) {
        int kr = (n << 4) + c16;
        sv8 k0 = *(const sv8*)&kbuf[buf][kr * 64 + ((g ^ (kr & 7)) << 3)];
        s[n] = __builtin_amdgcn_mfma_f32_16x16x32_bf16(k0, qa0, s[n], 0, 0, 0);
        sv8 k1 = *(const sv8*)&kbuf[buf][kr * 64 + (((4 + g) ^ (kr & 7)) << 3)];
        s[n] = __builtin_amdgcn_mfma_f32_16x16x32_bf16(k1, qa1, s[n], 0, 0, 0);
      }

      // ---- mask only on the diagonal tile ----
      if (t == qb) {
        #pragma unroll
        for (int n = 0; n < 4; ++n) {
          int key = (t << 6) + (n << 4) + (g << 2);
          #pragma unroll
          for (int r = 0; r < 4; ++r)
            s[n][r] = (key + r <= qrow) ? s[n][r] : -1e30f;
        }
      }

      // ---- per-lane online softmax (row = q = c16; reduce over lane>>4) ----
      float mx = -1e30f;
      #pragma unroll
      for (int n = 0; n < 4; ++n)
        mx = fmaxf(mx, fmaxf(fmaxf(s[n][0], s[n][1]), fmaxf(s[n][2], s[n][3])));
      mx = fmaxf(mx, __shfl_xor(mx, 16));
      mx = fmaxf(mx, __shfl_xor(mx, 32));
      float mnew  = fmaxf(m, mx);
      float alpha = __expf(m - mnew);
      m = mnew;

      float sum = 0.f;
      #pragma unroll
      for (int n = 0; n < 4; ++n) {
        float p0 = __expf(s[n][0] - mnew);
        float p1 = __expf(s[n][1] - mnew);
        float p2 = __expf(s[n][2] - mnew);
        float p3 = __expf(s[n][3] - mnew);
        sum += (p0 + p1) + (p2 + p3);
        int slot = 2 * n + (g >> 1);
        uint2 w2; w2.x = pk2(p0, p1); w2.y = pk2(p2, p3);
        *(uint2*)&br[c16 * 64 + ((slot ^ sx) << 3) + (g & 1) * 4] = w2;
      }
      sum += __shfl_xor(sum, 16);
      sum += __shfl_xor(sum, 32);
      l = l * alpha + sum;

      // ---- O rescale: D-rows 4g+r use alpha of q-row 4g+r ----
      float af[4];
      #pragma unroll
      for (int r = 0; r < 4; ++r) af[r] = __shfl(alpha, (g << 2) + r);
      #pragma unroll
      for (int n = 0; n < 4; ++n)
        #pragma unroll
        for (int r = 0; r < 4; ++r) o[n][r] *= af[r];

      asm volatile("s_waitcnt lgkmcnt(0)" ::: "memory");
      __builtin_amdgcn_sched_barrier(0);

      // ---- O += P V ----
      #pragma unroll
      for (int kk = 0; kk < 2; ++kk) {
        sv8 pa = *(const sv8*)&br[c16 * 64 + ((((kk << 2) + g) ^ sx) << 3)];
        #pragma unroll
        for (int n = 0; n < 4; ++n) {
          int vr = (n << 4) + c16;
          sv8 vf = *(const sv8*)&vbuf[buf][vr * 64 +
                                           ((((kk << 2) + g) ^ (vr & 7)) << 3)];
          o[n] = __builtin_amdgcn_mfma_f32_16x16x32_bf16(pa, vf, o[n], 0, 0, 0);
        }
      }

      if (t + 1 < t1) {
        asm volatile("s_waitcnt vmcnt(0)" ::: "memory");
        __builtin_amdgcn_sched_barrier(0);
        __builtin_amdgcn_s_barrier();
      }
    }
  }

  // ---- write partials ----
  #pragma unroll
  for (int n = 0; n < 4; ++n) {
    #pragma unroll
    for (int r = 0; r < 4; ++r) {
      int row = (wid << 4) + (g << 2) + r;
      Opart[(size_t)bid * 4096 + row * 64 + (n << 4) + c16] = o[n][r];
    }
  }
  if (lane < 16) {
    int row = (wid << 4) + lane;
    mlws[((size_t)bid * 64 + row) * 2]     = m;
    mlws[((size_t)bid * 64 + row) * 2 + 1] = l;
  }
  #undef STAGE
}

// ---------------- Kernel 3: split-K combine ----------------
// 256 blocks (batch, qb) x 256 threads: thread = (row, 16 cols).
__global__ __launch_bounds__(256) void combine(
    const float* __restrict__ Opart,
    const float* __restrict__ mlws,
    float* __restrict__ out)
{
  const int bid   = blockIdx.x;
  const int batch = bid & 7;
  const int qb    = bid >> 3;
  const int q0    = qb << 6;
  const int bid0  = bid;
  const int bid1  = 256 + ((31 - qb) << 3) + batch;

  const int tid = threadIdx.x;
  const int row = tid >> 2;
  const int cs  = (tid & 3) << 4;

  float m0 = mlws[((size_t)bid0 * 64 + row) * 2];
  float l0 = mlws[((size_t)bid0 * 64 + row) * 2 + 1];
  float m1 = mlws[((size_t)bid1 * 64 + row) * 2];
  float l1 = mlws[((size_t)bid1 * 64 + row) * 2 + 1];
  float M  = fmaxf(m0, m1);
  float a0 = __expf(m0 - M), a1 = __expf(m1 - M);
  float invL = 1.f / (l0 * a0 + l1 * a1);

  const float* O0 = Opart + (size_t)bid0 * 4096 + row * 64 + cs;
  const float* O1 = Opart + (size_t)bid1 * 4096 + row * 64 + cs;
  float* op = out + ((size_t)batch * TSEQ + q0 + row) * HD + cs;

  #pragma unroll
  for (int e = 0; e < 4; ++e) {
    float4 v0 = *(const float4*)(O0 + e * 4);
    float4 v1 = *(const float4*)(O1 + e * 4);
    float4 res;
    res.x = (v0.x * a0 + v1.x * a1) * invL;
    res.y = (v0.y * a0 + v1.y * a1) * invL;
    res.z = (v0.z * a0 + v1.z * a1) * invL;
    res.w = (v0.w * a0 + v1.w * a1) * invL;
    *(float4*)(op + e * 4) = res;
  }
}

extern "C" void kernel_launch(void* const* d_in, const int* in_sizes, int n_in,
                              void* d_out, int out_size, void* d_ws, size_t ws_size,
                              hipStream_t stream) {
  const float* x  = (const float*)d_in[0];
  const float* Wk = (const float*)d_in[1];
  const float* Wq = (const float*)d_in[2];
  const float* Wv = (const float*)d_in[3];
  float* out = (float*)d_out;

  short* qw  = (short*)d_ws;                        // 2 MB
  short* kw  = qw + (size_t)MROWS * HD;             // 2 MB (swizzled)
  short* vtw = kw + (size_t)MROWS * HD;             // 2 MB (tiled+swizzled)
  short* wb  = vtw + (size_t)NB * HD * TSEQ;        // 384 KB (pre-swizzled)
  float* Opart = (float*)(wb + 24576 * 8);          // 8 MB
  float* mlws  = Opart + (size_t)512 * 4096;        // 256 KB

  wcvt<<<dim3(96), dim3(256), 0, stream>>>(Wq, Wk, Wv, wb);
  qkv_proj<<<dim3(MROWS / 64), dim3(1024), 0, stream>>>(x, wb, qw, kw, vtw);
  attn<<<dim3(512), dim3(256), 0, stream>>>(qw, kw, vtw, Opart, mlws);
  combine<<<dim3(256), dim3(256), 0, stream>>>(Opart, mlws, out);
}

// Round 7
// 51.624 us; speedup vs baseline: 1.3624x; 1.1175x over previous
//
#include <hip/hip_runtime.h>

// B=8, T=2048, C=1024, H=64 single-head causal attention, f32 in/out.
// Round 7: fatter phases, fewer drains. qkv K-chunk 128 (8 barriers, counted
// vmcnt(2)); attn KVBLK 128 (half the barriers, setprio around MFMA).

typedef __attribute__((ext_vector_type(4))) short sv4;
typedef __attribute__((ext_vector_type(8))) short sv8;
typedef __attribute__((ext_vector_type(4))) float f32x4;

#define NB   8
#define TSEQ 2048
#define CDIM 1024
#define HD   64
#define MROWS (NB * TSEQ)   // 16384

__device__ __forceinline__ short f2s(float f) {
  union { float f; unsigned u; } v; v.f = f;
  unsigned u = v.u;
  u += 0x7fffu + ((u >> 16) & 1u);
  return (short)(u >> 16);
}
__device__ __forceinline__ unsigned pk2(float lo, float hi) {
  return (unsigned)(unsigned short)f2s(lo) | ((unsigned)(unsigned short)f2s(hi) << 16);
}
__device__ __forceinline__ void glds16(const short* g, short* l) {
  __builtin_amdgcn_global_load_lds(
      (const __attribute__((address_space(1))) unsigned int*)g,
      (__attribute__((address_space(3))) unsigned int*)l, 16, 0, 0);
}

// ---------------- Kernel 0: W f32 -> bf16, pre-swizzled 128-chunk images ----
// wb: chunk t (128 K-cols), r = j*64+wrow (0..191), slot s (0..15):
//   wb[((t*192 + r)*16 + s)*8 + e] = W[j][wrow][t*128 + ((s^(wrow&7))<<3) + e]
__global__ __launch_bounds__(256) void wcvt(
    const float* __restrict__ Wq, const float* __restrict__ Wk,
    const float* __restrict__ Wv, short* __restrict__ wb)
{
  int i = blockIdx.x * 256 + threadIdx.x;   // 0..24575
  int t = i / 3072;                         // 8 chunks x 3072 sv8
  int rem = i - t * 3072;
  int r = rem >> 4, s = rem & 15;
  int j = r >> 6, wrow = r & 63;
  const float* W = (j == 0) ? Wq : (j == 1) ? Wk : Wv;
  const float* src = W + (size_t)wrow * CDIM + t * 128 + ((s ^ (wrow & 7)) << 3);
  float4 a = *(const float4*)src;
  float4 b = *(const float4*)(src + 4);
  sv8 v = {f2s(a.x), f2s(a.y), f2s(a.z), f2s(a.w),
           f2s(b.x), f2s(b.y), f2s(b.z), f2s(b.w)};
  *(sv8*)(wb + (size_t)i * 8) = v;
}

// ---------------- Kernel 1: QKV projection ----------------
// 256 blocks x 1024 threads (16 waves). Block = 64 rows, 192 out cols.
// K-chunks of 128: per thread per chunk exactly 3 W-glds + 2 x-loads + 1 ds_write.
__global__ __launch_bounds__(1024) void qkv_proj(
    const float* __restrict__ x,
    const short* __restrict__ wb,
    short* __restrict__ qw,
    short* __restrict__ kw,
    short* __restrict__ vtw)
{
  __shared__ short wlds[2][24576];  // 96 KB
  __shared__ short xlds[2][8192];   // 32 KB
  const int tid  = threadIdx.x;
  const int wid  = tid >> 6;
  const int lane = tid & 63;
  const int g    = lane >> 4;
  const int c16  = lane & 15;
  const int rowg = wid >> 2;
  const int ph   = wid & 3;
  const int row0 = blockIdx.x * 64;

  // x loader: thread = (row xr, slot xs of 8 f32)
  const int xr = tid >> 4, xs = tid & 15;
  const float* xsrc = x + (size_t)(row0 + xr) * CDIM + xs * 8;
  const int xwo = xr * 128 + ((xs ^ (xr & 7)) << 3);

  const int arow = rowg * 16 + c16;
  const int x7   = arow & 7;
  int rWo[3], rW7[3];
  #pragma unroll
  for (int p6 = 0; p6 < 3; ++p6) {
    int p = ph * 3 + p6;
    int r = (p >> 2) * 64 + (p & 3) * 16 + c16;
    rWo[p6] = r * 128;
    rW7[p6] = r & 7;
  }

  f32x4 acc[3];
  #pragma unroll
  for (int p6 = 0; p6 < 3; ++p6) acc[p6] = (f32x4){0.f, 0.f, 0.f, 0.f};

  float4 px[2][2];

  // ---- prologue: stage W(0), load x(0),x(1), write x(0) ----
  #pragma unroll
  for (int k2 = 0; k2 < 3; ++k2)
    glds16(wb + (size_t)(tid + k2 * 1024) * 8, &wlds[0][(tid + k2 * 1024) * 8]);
  px[0][0] = *(const float4*)(xsrc);
  px[0][1] = *(const float4*)(xsrc + 4);
  px[1][0] = *(const float4*)(xsrc + 128);
  px[1][1] = *(const float4*)(xsrc + 132);
  asm volatile("s_waitcnt vmcnt(2)" ::: "memory");   // W(0)+x(0) done
  {
    float4 A = px[0][0], B = px[0][1];
    sv8 v = {f2s(A.x), f2s(A.y), f2s(A.z), f2s(A.w),
             f2s(B.x), f2s(B.y), f2s(B.z), f2s(B.w)};
    *(sv8*)&xlds[0][xwo] = v;
  }
  asm volatile("s_waitcnt lgkmcnt(0)" ::: "memory");
  __builtin_amdgcn_sched_barrier(0);
  __builtin_amdgcn_s_barrier();

  #pragma unroll
  for (int t = 0; t < 8; ++t) {
    const int buf = t & 1;
    if (t < 7) {   // stage W(t+1)
      #pragma unroll
      for (int k2 = 0; k2 < 3; ++k2)
        glds16(wb + (size_t)((t + 1) * 3072 + tid + k2 * 1024) * 8,
               &wlds[buf ^ 1][(tid + k2 * 1024) * 8]);
    }
    if (t < 6) {   // load x(t+2)
      px[t & 1][0] = *(const float4*)(xsrc + (t + 2) * 128);
      px[t & 1][1] = *(const float4*)(xsrc + (t + 2) * 128 + 4);
    }
    if (t < 7) {   // write x(t+1)
      float4 A = px[(t + 1) & 1][0], B = px[(t + 1) & 1][1];
      sv8 v = {f2s(A.x), f2s(A.y), f2s(A.z), f2s(A.w),
               f2s(B.x), f2s(B.y), f2s(B.z), f2s(B.w)};
      *(sv8*)&xlds[buf ^ 1][xwo] = v;
    }
    // ---- compute chunk t: 12 MFMA/wave ----
    #pragma unroll
    for (int kk = 0; kk < 4; ++kk) {
      int kslot = kk * 4 + g;
      sv8 a = *(const sv8*)&xlds[buf][arow * 128 + ((kslot ^ x7) << 3)];
      #pragma unroll
      for (int p6 = 0; p6 < 3; ++p6) {
        sv8 bfr = *(const sv8*)&wlds[buf][rWo[p6] + ((kslot ^ rW7[p6]) << 3)];
        acc[p6] = __builtin_amdgcn_mfma_f32_16x16x32_bf16(a, bfr, acc[p6], 0, 0, 0);
      }
    }
    if (t < 7) {
      // drain W(t+1) + x ds_write; keep x(t+2) loads (2) in flight
      if (t < 6) asm volatile("s_waitcnt vmcnt(2) lgkmcnt(0)" ::: "memory");
      else       asm volatile("s_waitcnt vmcnt(0) lgkmcnt(0)" ::: "memory");
      __builtin_amdgcn_sched_barrier(0);
      __builtin_amdgcn_s_barrier();
    }
  }

  // ---- epilogue: D row = 4g+r, col = 16n+c16 ----
  #pragma unroll
  for (int p6 = 0; p6 < 3; ++p6) {
    int p = ph * 3 + p6, j = p >> 2, n = p & 3;
    #pragma unroll
    for (int r = 0; r < 4; ++r) {
      int rr = row0 + rowg * 16 + (g << 2) + r;
      int cc = (n << 4) + c16;
      if (j == 0) {
        qw[(size_t)rr * HD + cc] = f2s(acc[p6][r] * 0.03125f);
      } else if (j == 1) {
        kw[(size_t)rr * HD + ((((cc >> 3) ^ (rr & 7)) << 3) | (cc & 7))] =
            f2s(acc[p6][r]);
      } else {
        int b = rr >> 11, ti = rr & (TSEQ - 1);
        int kt = ti >> 6, key = ti & 63;
        vtw[(((size_t)b * 32 + kt) * 64 + cc) * 64 +
            ((((key >> 3) ^ (cc & 7)) << 3) | (key & 7))] = f2s(acc[p6][r]);
      }
    }
  }
}

// ---------------- Kernel 2: flash attention, KVBLK=128 ----------------
// 512 blocks x 4 waves. Block = (batch, qb 64-row q-block, half h).
// 128-key tiles shared via LDS (glds from pre-swizzled images), dbuf,
// one barrier per tile. Partials -> workspace; combine kernel merges.
__global__ __launch_bounds__(256) void attn(
    const short* __restrict__ qw,
    const short* __restrict__ kw,
    const short* __restrict__ vtw,
    float* __restrict__ Opart,
    float* __restrict__ mlws)
{
  __shared__ short kbuf[2][8192];     // 32 KB
  __shared__ short vbuf[2][8192];     // 32 KB
  __shared__ short bridge[4][2048];   // 16 KB, per-wave P bridge

  const int tid  = threadIdx.x;
  const int wid  = tid >> 6;
  const int lane = tid & 63;
  const int g    = lane >> 4;
  const int c16  = lane & 15;

  const int bid   = blockIdx.x;
  const int h     = bid >> 8;
  const int sub   = bid & 255;
  const int batch = sub & 7;
  const int jj    = sub >> 3;
  const int qb    = h ? (31 - jj) : jj;
  const int q0    = qb << 6;
  const size_t base = (size_t)batch * TSEQ * HD;

  const int ntot = (qb >> 1) + 1;        // 128-key tiles
  const int th_  = (ntot + 1) >> 1;
  const int t0   = h ? th_ : 0;
  const int t1   = h ? ntot : th_;

  const int qrow = q0 + (wid << 4) + c16;
  sv8 qa0 = *(const sv8*)(qw + base + (size_t)qrow * HD + (g << 3));
  sv8 qa1 = *(const sv8*)(qw + base + (size_t)qrow * HD + 32 + (g << 3));

  float m = -1e30f, l = 0.f;
  f32x4 o[4];
  #pragma unroll
  for (int n = 0; n < 4; ++n) o[n] = (f32x4){0.f, 0.f, 0.f, 0.f};

  short* br = &bridge[wid][0];
  const int sx = c16 & 15;

  #define STAGE(tt, bb)                                                      \
    {                                                                        \
      const short* ksrc = kw + base + (size_t)(tt) * 8192;                   \
      const short* vsrc = vtw + ((size_t)batch * 32 + (tt) * 2) * 4096;      \
      _Pragma("unroll")                                                      \
      for (int q = 0; q < 4; ++q)                                            \
        glds16(ksrc + (tid + q * 256) * 8, &kbuf[bb][(tid + q * 256) * 8]);  \
      _Pragma("unroll")                                                      \
      for (int q = 0; q < 4; ++q)                                            \
        glds16(vsrc + (tid + q * 256) * 8, &vbuf[bb][(tid + q * 256) * 8]);  \
    }

  if (t0 < t1) {
    STAGE(t0, 0);
    asm volatile("s_waitcnt vmcnt(0)" ::: "memory");
    __builtin_amdgcn_s_barrier();

    for (int t = t0; t < t1; ++t) {
      const int buf = (t - t0) & 1;
      if (t + 1 < t1) STAGE(t + 1, buf ^ 1);

      // ---- S^T = mfma(K, Q): D[row=key 0..127, col=q] ----
      f32x4 s[8];
      #pragma unroll
      for (int n = 0; n < 8; ++n) s[n] = (f32x4){0.f, 0.f, 0.f, 0.f};
      __builtin_amdgcn_s_setprio(1);
      #pragma unroll
      for (int n = 0; n < 8; ++n) {
        int kr = (n << 4) + c16;
        sv8 k0 = *(const sv8*)&kbuf[buf][kr * 64 + ((g ^ (kr & 7)) << 3)];
        s[n] = __builtin_amdgcn_mfma_f32_16x16x32_bf16(k0, qa0, s[n], 0, 0, 0);
        sv8 k1 = *(const sv8*)&kbuf[buf][kr * 64 + (((4 + g) ^ (kr & 7)) << 3)];
        s[n] = __builtin_amdgcn_mfma_f32_16x16x32_bf16(k1, qa1, s[n], 0, 0, 0);
      }
      __builtin_amdgcn_s_setprio(0);

      // ---- mask only on the diagonal 128-tile ----
      if (t == (qb >> 1)) {
        #pragma unroll
        for (int n = 0; n < 8; ++n) {
          int key = (t << 7) + (n << 4) + (g << 2);
          #pragma unroll
          for (int r = 0; r < 4; ++r)
            s[n][r] = (key + r <= qrow) ? s[n][r] : -1e30f;
        }
      }

      // ---- per-lane online softmax (lane owns q-row; reduce over lane>>4) ----
      float mx = -1e30f;
      #pragma unroll
      for (int n = 0; n < 8; ++n)
        mx = fmaxf(mx, fmaxf(fmaxf(s[n][0], s[n][1]), fmaxf(s[n][2], s[n][3])));
      mx = fmaxf(mx, __shfl_xor(mx, 16));
      mx = fmaxf(mx, __shfl_xor(mx, 32));
      float mnew  = fmaxf(m, mx);
      float alpha = __expf(m - mnew);
      m = mnew;

      float sum = 0.f;
      #pragma unroll
      for (int n = 0; n < 8; ++n) {
        float p0 = __expf(s[n][0] - mnew);
        float p1 = __expf(s[n][1] - mnew);
        float p2 = __expf(s[n][2] - mnew);
        float p3 = __expf(s[n][3] - mnew);
        sum += (p0 + p1) + (p2 + p3);
        int slot = 2 * n + (g >> 1);
        uint2 w2; w2.x = pk2(p0, p1); w2.y = pk2(p2, p3);
        *(uint2*)&br[c16 * 128 + ((slot ^ sx) << 3) + ((g & 1) << 2)] = w2;
      }
      sum += __shfl_xor(sum, 16);
      sum += __shfl_xor(sum, 32);
      l = l * alpha + sum;

      // ---- O rescale: D-rows 4g+r use alpha of q-row 4g+r ----
      float af[4];
      #pragma unroll
      for (int r = 0; r < 4; ++r) af[r] = __shfl(alpha, (g << 2) + r);
      #pragma unroll
      for (int n = 0; n < 4; ++n)
        #pragma unroll
        for (int r = 0; r < 4; ++r) o[n][r] *= af[r];

      asm volatile("s_waitcnt lgkmcnt(0)" ::: "memory");
      __builtin_amdgcn_sched_barrier(0);

      // ---- O += P V (128 keys) ----
      __builtin_amdgcn_s_setprio(1);
      #pragma unroll
      for (int kk = 0; kk < 4; ++kk) {
        int kslot = (kk << 2) + g;
        sv8 pa = *(const sv8*)&br[c16 * 128 + ((kslot ^ sx) << 3)];
        #pragma unroll
        for (int n = 0; n < 4; ++n) {
          int vr = (n << 4) + c16;
          sv8 vf = *(const sv8*)&vbuf[buf][(kslot >> 3) * 4096 + vr * 64 +
                                           (((kslot & 7) ^ (vr & 7)) << 3)];
          o[n] = __builtin_amdgcn_mfma_f32_16x16x32_bf16(pa, vf, o[n], 0, 0, 0);
        }
      }
      __builtin_amdgcn_s_setprio(0);

      if (t + 1 < t1) {
        asm volatile("s_waitcnt vmcnt(0)" ::: "memory");
        __builtin_amdgcn_sched_barrier(0);
        __builtin_amdgcn_s_barrier();
      }
    }
  }

  // ---- write partials ----
  #pragma unroll
  for (int n = 0; n < 4; ++n) {
    #pragma unroll
    for (int r = 0; r < 4; ++r) {
      int row = (wid << 4) + (g << 2) + r;
      Opart[(size_t)bid * 4096 + row * 64 + (n << 4) + c16] = o[n][r];
    }
  }
  if (lane < 16) {
    int row = (wid << 4) + lane;
    mlws[((size_t)bid * 64 + row) * 2]     = m;
    mlws[((size_t)bid * 64 + row) * 2 + 1] = l;
  }
  #undef STAGE
}

// ---------------- Kernel 3: split-K combine ----------------
__global__ __launch_bounds__(256) void combine(
    const float* __restrict__ Opart,
    const float* __restrict__ mlws,
    float* __restrict__ out)
{
  const int bid   = blockIdx.x;
  const int batch = bid & 7;
  const int qb    = bid >> 3;
  const int q0    = qb << 6;
  const int bid0  = bid;
  const int bid1  = 256 + ((31 - qb) << 3) + batch;

  const int tid = threadIdx.x;
  const int row = tid >> 2;
  const int cs  = (tid & 3) << 4;

  float m0 = mlws[((size_t)bid0 * 64 + row) * 2];
  float l0 = mlws[((size_t)bid0 * 64 + row) * 2 + 1];
  float m1 = mlws[((size_t)bid1 * 64 + row) * 2];
  float l1 = mlws[((size_t)bid1 * 64 + row) * 2 + 1];
  float M  = fmaxf(m0, m1);
  float a0 = __expf(m0 - M), a1 = __expf(m1 - M);
  float invL = 1.f / (l0 * a0 + l1 * a1);

  const float* O0 = Opart + (size_t)bid0 * 4096 + row * 64 + cs;
  const float* O1 = Opart + (size_t)bid1 * 4096 + row * 64 + cs;
  float* op = out + ((size_t)batch * TSEQ + q0 + row) * HD + cs;

  #pragma unroll
  for (int e = 0; e < 4; ++e) {
    float4 v0 = *(const float4*)(O0 + e * 4);
    float4 v1 = *(const float4*)(O1 + e * 4);
    float4 res;
    res.x = (v0.x * a0 + v1.x * a1) * invL;
    res.y = (v0.y * a0 + v1.y * a1) * invL;
    res.z = (v0.z * a0 + v1.z * a1) * invL;
    res.w = (v0.w * a0 + v1.w * a1) * invL;
    *(float4*)(op + e * 4) = res;
  }
}

extern "C" void kernel_launch(void* const* d_in, const int* in_sizes, int n_in,
                              void* d_out, int out_size, void* d_ws, size_t ws_size,
                              hipStream_t stream) {
  const float* x  = (const float*)d_in[0];
  const float* Wk = (const float*)d_in[1];
  const float* Wq = (const float*)d_in[2];
  const float* Wv = (const float*)d_in[3];
  float* out = (float*)d_out;

  short* qw  = (short*)d_ws;                        // 2 MB
  short* kw  = qw + (size_t)MROWS * HD;             // 2 MB (row-swizzled)
  short* vtw = kw + (size_t)MROWS * HD;             // 2 MB (tiled+swizzled)
  short* wb  = vtw + (size_t)NB * HD * TSEQ;        // 384 KB (pre-swizzled)
  float* Opart = (float*)(wb + 24576 * 8);          // 8 MB
  float* mlws  = Opart + (size_t)512 * 4096;        // 256 KB

  wcvt<<<dim3(96), dim3(256), 0, stream>>>(Wq, Wk, Wv, wb);
  qkv_proj<<<dim3(MROWS / 64), dim3(1024), 0, stream>>>(x, wb, qw, kw, vtw);
  attn<<<dim3(512), dim3(256), 0, stream>>>(qw, kw, vtw, Opart, mlws);
  combine<<<dim3(256), dim3(256), 0, stream>>>(Opart, mlws, out);
}